// Round 3
// baseline (510.542 us; speedup 1.0000x reference)
//
#include <hip/hip_runtime.h>
#include <hip/hip_bf16.h>

// GraphSAGE 3-layer, N=50000, d=64, E=800000, fp32.
// R3: atomic-free CSR build via dst-range partitioning.
//   K1 deg_range: block owns 250 dsts, scans all dst[], LDS hist -> deg + partial
//   K2 scan_ranges: exclusive scan of 200 range totals
//   K3 scatter_range: re-scan dst[], LDS cursors, contiguous ushort csr writes
// Then per layer: agg (wave-per-node pull mean), gemm (fp32 VALU, LDS-tiled).

#define D 64
#define NRANGE 200      // blocks in build kernels
#define RSZ 250         // dsts per range (NRANGE*RSZ = 50000)
#define BT 1024         // build-kernel block size

// ---------------- CSR build ----------------

__global__ __launch_bounds__(BT)
void deg_range_kernel(const int* __restrict__ dst, int* __restrict__ deg,
                      int* __restrict__ partial, int n_edges) {
    __shared__ int hist[256];
    const int t = threadIdx.x;
    const int lo = blockIdx.x * RSZ;
    if (t < 256) hist[t] = 0;
    __syncthreads();

    for (int base = 0; base < n_edges; base += 4 * BT) {
        int e0 = base + t, e1 = e0 + BT, e2 = e1 + BT, e3 = e2 + BT;
        int d0 = (e0 < n_edges) ? dst[e0] : -1;
        int d1 = (e1 < n_edges) ? dst[e1] : -1;
        int d2 = (e2 < n_edges) ? dst[e2] : -1;
        int d3 = (e3 < n_edges) ? dst[e3] : -1;
        if ((unsigned)(d0 - lo) < (unsigned)RSZ) atomicAdd(&hist[d0 - lo], 1);
        if ((unsigned)(d1 - lo) < (unsigned)RSZ) atomicAdd(&hist[d1 - lo], 1);
        if ((unsigned)(d2 - lo) < (unsigned)RSZ) atomicAdd(&hist[d2 - lo], 1);
        if ((unsigned)(d3 - lo) < (unsigned)RSZ) atomicAdd(&hist[d3 - lo], 1);
    }
    __syncthreads();
    if (t < RSZ) deg[lo + t] = hist[t];
    // reduce hist[0..255] -> partial[b]
    for (int off = 128; off > 0; off >>= 1) {
        if (t < off) hist[t] += hist[t + off];
        __syncthreads();
    }
    if (t == 0) partial[blockIdx.x] = hist[0];
}

__global__ __launch_bounds__(256)
void scan_ranges_kernel(const int* __restrict__ partial,
                        int* __restrict__ range_base,
                        int* __restrict__ offsets, int n_nodes) {
    __shared__ int s[256];
    const int t = threadIdx.x;
    int v = (t < NRANGE) ? partial[t] : 0;
    s[t] = v;
    __syncthreads();
#pragma unroll
    for (int off = 1; off < 256; off <<= 1) {
        int u = 0;
        if (t >= off) u = s[t - off];
        __syncthreads();
        if (t >= off) s[t] += u;
        __syncthreads();
    }
    if (t < NRANGE) range_base[t] = (t > 0) ? s[t - 1] : 0;
    if (t == 0) offsets[n_nodes] = s[255];
}

__global__ __launch_bounds__(BT)
void scatter_range_kernel(const int* __restrict__ src, const int* __restrict__ dst,
                          const int* __restrict__ deg, const int* __restrict__ range_base,
                          int* __restrict__ offsets, unsigned short* __restrict__ csr,
                          int n_edges) {
    __shared__ int s[256];
    __shared__ int cur[RSZ];
    const int t = threadIdx.x;
    const int lo = blockIdx.x * RSZ;

    if (t < 256) s[t] = (t < RSZ) ? deg[lo + t] : 0;
    __syncthreads();
    // inclusive scan of s[0..255]
#pragma unroll
    for (int off = 1; off < 256; off <<= 1) {
        int u = 0;
        if (t < 256 && t >= off) u = s[t - off];
        __syncthreads();
        if (t < 256 && t >= off) s[t] += u;
        __syncthreads();
    }
    const int base = range_base[blockIdx.x];
    if (t < RSZ) {
        int excl = base + ((t > 0) ? s[t - 1] : 0);
        cur[t] = excl;
        offsets[lo + t] = excl;
    }
    __syncthreads();

    for (int bb = 0; bb < n_edges; bb += 4 * BT) {
        int e0 = bb + t, e1 = e0 + BT, e2 = e1 + BT, e3 = e2 + BT;
        int d0 = (e0 < n_edges) ? dst[e0] : -1;
        int d1 = (e1 < n_edges) ? dst[e1] : -1;
        int d2 = (e2 < n_edges) ? dst[e2] : -1;
        int d3 = (e3 < n_edges) ? dst[e3] : -1;
        if ((unsigned)(d0 - lo) < (unsigned)RSZ) {
            int p = atomicAdd(&cur[d0 - lo], 1);
            csr[p] = (unsigned short)src[e0];
        }
        if ((unsigned)(d1 - lo) < (unsigned)RSZ) {
            int p = atomicAdd(&cur[d1 - lo], 1);
            csr[p] = (unsigned short)src[e1];
        }
        if ((unsigned)(d2 - lo) < (unsigned)RSZ) {
            int p = atomicAdd(&cur[d2 - lo], 1);
            csr[p] = (unsigned short)src[e2];
        }
        if ((unsigned)(d3 - lo) < (unsigned)RSZ) {
            int p = atomicAdd(&cur[d3 - lo], 1);
            csr[p] = (unsigned short)src[e3];
        }
    }
}

// ---------------- Per-layer kernels ----------------

// One wave per node; lane = feature. Mean of neighbor rows.
__global__ __launch_bounds__(256)
void agg_kernel(const float* __restrict__ h, const int* __restrict__ offsets,
                const unsigned short* __restrict__ csr, float* __restrict__ mean,
                int n_nodes) {
    int wid = (int)((blockIdx.x * (unsigned)blockDim.x + threadIdx.x) >> 6);
    int lane = threadIdx.x & 63;
    if (wid >= n_nodes) return;
    int beg = offsets[wid];
    int end = offsets[wid + 1];
    float acc = 0.0f;
    int i = beg;
    for (; i + 4 <= end; i += 4) {
        int s0 = csr[i], s1 = csr[i + 1], s2 = csr[i + 2], s3 = csr[i + 3];
        float v0 = h[s0 * D + lane];
        float v1 = h[s1 * D + lane];
        float v2 = h[s2 * D + lane];
        float v3 = h[s3 * D + lane];
        acc += v0 + v1 + v2 + v3;
    }
    for (; i < end; i++) acc += h[(int)csr[i] * D + lane];
    float c = (float)max(end - beg, 1);
    mean[wid * D + lane] = acc / c;
}

// out[n][j] = sum_k mean[n][k]*Wl[k][j] + h[n][k]*Wr[k][j] + b[j], optional ReLU.
#define M_TILE 64

__global__ __launch_bounds__(256)
void gemm_kernel(const float* __restrict__ mean, const float* __restrict__ h,
                 const float* __restrict__ Wl, const float* __restrict__ Wr,
                 const float* __restrict__ bias, float* __restrict__ out,
                 int relu, int n_nodes) {
    __shared__ float sWl[D * D];
    __shared__ float sWr[D * D];
    __shared__ float sAm[M_TILE * D];
    __shared__ float sAh[M_TILE * D];

    const int t = threadIdx.x;
    const int n0 = blockIdx.x * M_TILE;

    {
        const float4* wl4 = (const float4*)Wl;
        const float4* wr4 = (const float4*)Wr;
        float4* sWl4 = (float4*)sWl;
        float4* sWr4 = (float4*)sWr;
        for (int i = t; i < 1024; i += 256) {
            sWl4[i] = wl4[i];
            sWr4[i] = wr4[i];
        }
    }
    {
        float4* sAm4 = (float4*)sAm;
        float4* sAh4 = (float4*)sAh;
        const float4* m4 = (const float4*)mean;
        const float4* h4 = (const float4*)h;
        for (int i = t; i < M_TILE * (D / 4); i += 256) {
            int row = i / (D / 4);
            int col = i % (D / 4);
            int node = n0 + row;
            if (node < n_nodes) {
                sAm4[i] = m4[node * (D / 4) + col];
                sAh4[i] = h4[node * (D / 4) + col];
            } else {
                sAm4[i] = make_float4(0.f, 0.f, 0.f, 0.f);
                sAh4[i] = make_float4(0.f, 0.f, 0.f, 0.f);
            }
        }
    }
    __syncthreads();

    const int jp = (t & 31) * 2;
    const int nb = (t >> 5) * 8;

    float acc0[8], acc1[8];
#pragma unroll
    for (int i = 0; i < 8; i++) { acc0[i] = 0.f; acc1[i] = 0.f; }

    for (int k = 0; k < D; k += 4) {
        float2 wl[4], wr[4];
#pragma unroll
        for (int kk = 0; kk < 4; kk++) {
            wl[kk] = *(const float2*)&sWl[(k + kk) * D + jp];
            wr[kk] = *(const float2*)&sWr[(k + kk) * D + jp];
        }
#pragma unroll
        for (int i = 0; i < 8; i++) {
            float4 m4 = *(const float4*)&sAm[(nb + i) * D + k];
            float4 h4 = *(const float4*)&sAh[(nb + i) * D + k];
            acc0[i] += m4.x * wl[0].x + h4.x * wr[0].x;
            acc0[i] += m4.y * wl[1].x + h4.y * wr[1].x;
            acc0[i] += m4.z * wl[2].x + h4.z * wr[2].x;
            acc0[i] += m4.w * wl[3].x + h4.w * wr[3].x;
            acc1[i] += m4.x * wl[0].y + h4.x * wr[0].y;
            acc1[i] += m4.y * wl[1].y + h4.y * wr[1].y;
            acc1[i] += m4.z * wl[2].y + h4.z * wr[2].y;
            acc1[i] += m4.w * wl[3].y + h4.w * wr[3].y;
        }
    }

    float b0 = bias[jp];
    float b1 = bias[jp + 1];
#pragma unroll
    for (int i = 0; i < 8; i++) {
        int node = n0 + nb + i;
        if (node < n_nodes) {
            float v0 = acc0[i] + b0;
            float v1 = acc1[i] + b1;
            if (relu) { v0 = fmaxf(v0, 0.f); v1 = fmaxf(v1, 0.f); }
            *(float2*)&out[node * D + jp] = make_float2(v0, v1);
        }
    }
}

extern "C" void kernel_launch(void* const* d_in, const int* in_sizes, int n_in,
                              void* d_out, int out_size, void* d_ws, size_t ws_size,
                              hipStream_t stream) {
    const float* x  = (const float*)d_in[0];
    const int*   ei = (const int*)d_in[1];
    const int n_nodes = in_sizes[0] / D;     // 50000
    const int n_edges = in_sizes[1] / 2;     // 800000
    const int* src = ei;
    const int* dst = ei + n_edges;

    const float* Wl1 = (const float*)d_in[2];
    const float* Wr1 = (const float*)d_in[3];
    const float* b1  = (const float*)d_in[4];
    const float* Wl2 = (const float*)d_in[5];
    const float* Wr2 = (const float*)d_in[6];
    const float* b2  = (const float*)d_in[7];
    const float* Wl3 = (const float*)d_in[8];
    const float* Wr3 = (const float*)d_in[9];
    const float* b3  = (const float*)d_in[10];

    // Workspace carve-up (256B aligned)
    char* w = (char*)d_ws;
    auto alloc = [&](size_t bytes) -> char* {
        char* p = w;
        w += (bytes + 255) & ~(size_t)255;
        return p;
    };
    int*   deg        = (int*)alloc((size_t)n_nodes * 4);
    int*   offsets    = (int*)alloc(((size_t)n_nodes + 1) * 4);
    int*   partial    = (int*)alloc(256 * 4);
    int*   range_base = (int*)alloc(256 * 4);
    unsigned short* csr = (unsigned short*)alloc((size_t)n_edges * 2);
    float* mean       = (float*)alloc((size_t)n_nodes * D * 4);
    float* h1         = (float*)alloc((size_t)n_nodes * D * 4);
    float* h2         = (float*)d_out;  // layer-3 gemm reads only its own tile rows before writing

    const int agg_blocks  = (n_nodes + 3) / 4;
    const int gemm_blocks = (n_nodes + M_TILE - 1) / M_TILE;

    // CSR build (atomic-free, dst-range partitioned)
    deg_range_kernel<<<NRANGE, BT, 0, stream>>>(dst, deg, partial, n_edges);
    scan_ranges_kernel<<<1, 256, 0, stream>>>(partial, range_base, offsets, n_nodes);
    scatter_range_kernel<<<NRANGE, BT, 0, stream>>>(src, dst, deg, range_base,
                                                    offsets, csr, n_edges);

    // Layer 1: x -> h1 (ReLU)
    agg_kernel<<<agg_blocks, 256, 0, stream>>>(x, offsets, csr, mean, n_nodes);
    gemm_kernel<<<gemm_blocks, 256, 0, stream>>>(mean, x, Wl1, Wr1, b1, h1, 1, n_nodes);

    // Layer 2: h1 -> h2 (ReLU)
    agg_kernel<<<agg_blocks, 256, 0, stream>>>(h1, offsets, csr, mean, n_nodes);
    gemm_kernel<<<gemm_blocks, 256, 0, stream>>>(mean, h1, Wl2, Wr2, b2, h2, 1, n_nodes);

    // Layer 3: h2 -> out (no activation)
    agg_kernel<<<agg_blocks, 256, 0, stream>>>(h2, offsets, csr, mean, n_nodes);
    gemm_kernel<<<gemm_blocks, 256, 0, stream>>>(mean, h2, Wl3, Wr3, b3, (float*)d_out, 0, n_nodes);
}

// Round 4
// 440.265 us; speedup vs baseline: 1.1596x; 1.1596x over previous
//
#include <hip/hip_runtime.h>
#include <hip/hip_bf16.h>

// GraphSAGE 3-layer, N=50000, d=64, E=800000, fp32.
// R4: back to O(E) atomic CSR build, but sharded 8-ways by blockIdx&7 so
// atomics/writes stay (heuristically) XCD-local -> kill the 16x write
// amplification R2's counters showed (52.8MB writes for a 3.2MB csr).
// Layout: deg8/offsets8/cursor8 are [shard][node] flat; flat exclusive scan
// gives each shard a contiguous private csr window. csr is ushort.
// Per layer: agg (wave-per-node pull mean over 8 segments), gemm (fp32 VALU).

#define D 64
#define NSHARD 8

// ---------------- CSR build ----------------

__global__ __launch_bounds__(256)
void zero_kernel(int* __restrict__ p, int n) {
    int i = blockIdx.x * blockDim.x + threadIdx.x;
    if (i < n) p[i] = 0;
}

__global__ __launch_bounds__(256)
void hist_kernel(const int* __restrict__ dst, int* __restrict__ deg8,
                 int n_edges, int n_nodes) {
    int e = blockIdx.x * blockDim.x + threadIdx.x;
    int g = blockIdx.x & (NSHARD - 1);
    if (e < n_edges) {
        int d = dst[e];
        if ((unsigned)d < (unsigned)n_nodes)
            atomicAdd(&deg8[g * n_nodes + d], 1);
    }
}

// Level 1: per-1024-chunk sums of deg8 (n_tot = 8*n_nodes entries).
__global__ __launch_bounds__(256)
void partial_kernel(const int* __restrict__ deg8, int* __restrict__ partial,
                    int n_tot) {
    __shared__ int s[256];
    int t = threadIdx.x;
    int base = blockIdx.x * 1024;
    int sum = 0;
#pragma unroll
    for (int k = 0; k < 4; k++) {
        int i = base + k * 256 + t;
        if (i < n_tot) sum += deg8[i];
    }
    s[t] = sum;
    __syncthreads();
#pragma unroll
    for (int off = 128; off > 0; off >>= 1) {
        if (t < off) s[t] += s[t + off];
        __syncthreads();
    }
    if (t == 0) partial[blockIdx.x] = s[0];
}

// Level 2: exclusive scan of (<=512) chunk partials; writes total.
__global__ __launch_bounds__(512)
void scan_partial_kernel(int* __restrict__ partial, int* __restrict__ offsets,
                         int nchunks, int n_tot) {
    __shared__ int s[512];
    int t = threadIdx.x;
    s[t] = (t < nchunks) ? partial[t] : 0;
    __syncthreads();
#pragma unroll
    for (int off = 1; off < 512; off <<= 1) {
        int u = 0;
        if (t >= off) u = s[t - off];
        __syncthreads();
        if (t >= off) s[t] += u;
        __syncthreads();
    }
    if (t < nchunks) partial[t] = (t > 0) ? s[t - 1] : 0;
    if (t == 0) offsets[n_tot] = s[511];
}

// Level 3: block-local scan of 1024 entries (4/thread) + chunk base.
__global__ __launch_bounds__(256)
void fill_kernel(const int* __restrict__ deg8, const int* __restrict__ partial,
                 int* __restrict__ offsets, int* __restrict__ cursor, int n_tot) {
    __shared__ int s[256];
    int t = threadIdx.x;
    int base = blockIdx.x * 1024;
    int i0 = base + 4 * t;
    int v0 = 0, v1 = 0, v2 = 0, v3 = 0;
    if (i0 + 3 < n_tot) {
        int4 v = *(const int4*)&deg8[i0];
        v0 = v.x; v1 = v.y; v2 = v.z; v3 = v.w;
    } else {
        if (i0 + 0 < n_tot) v0 = deg8[i0 + 0];
        if (i0 + 1 < n_tot) v1 = deg8[i0 + 1];
        if (i0 + 2 < n_tot) v2 = deg8[i0 + 2];
        if (i0 + 3 < n_tot) v3 = deg8[i0 + 3];
    }
    int mysum = v0 + v1 + v2 + v3;
    s[t] = mysum;
    __syncthreads();
#pragma unroll
    for (int off = 1; off < 256; off <<= 1) {
        int u = 0;
        if (t >= off) u = s[t - off];
        __syncthreads();
        if (t >= off) s[t] += u;
        __syncthreads();
    }
    int excl = partial[blockIdx.x] + ((t > 0) ? s[t - 1] : 0);
    int o0 = excl, o1 = o0 + v0, o2 = o1 + v1, o3 = o2 + v2;
    if (i0 + 3 < n_tot) {
        *(int4*)&offsets[i0] = make_int4(o0, o1, o2, o3);
        *(int4*)&cursor[i0]  = make_int4(o0, o1, o2, o3);
    } else {
        if (i0 + 0 < n_tot) { offsets[i0 + 0] = o0; cursor[i0 + 0] = o0; }
        if (i0 + 1 < n_tot) { offsets[i0 + 1] = o1; cursor[i0 + 1] = o1; }
        if (i0 + 2 < n_tot) { offsets[i0 + 2] = o2; cursor[i0 + 2] = o2; }
        if (i0 + 3 < n_tot) { offsets[i0 + 3] = o3; cursor[i0 + 3] = o3; }
    }
}

__global__ __launch_bounds__(256)
void scatter_kernel(const int* __restrict__ src, const int* __restrict__ dst,
                    int* __restrict__ cursor, unsigned short* __restrict__ csr,
                    int n_edges, int n_nodes) {
    int e = blockIdx.x * blockDim.x + threadIdx.x;
    int g = blockIdx.x & (NSHARD - 1);
    if (e < n_edges) {
        int d = dst[e];
        if ((unsigned)d < (unsigned)n_nodes) {
            int s = src[e];
            if ((unsigned)s >= (unsigned)n_nodes) s = 0;
            int p = atomicAdd(&cursor[g * n_nodes + d], 1);
            csr[p] = (unsigned short)s;
        }
    }
}

// ---------------- Per-layer kernels ----------------

// One wave per node; lane = feature. Mean over the node's 8 shard-segments.
__global__ __launch_bounds__(256)
void agg_kernel(const float* __restrict__ h, const int* __restrict__ offsets,
                const unsigned short* __restrict__ csr, float* __restrict__ mean,
                int n_nodes) {
    int wid = (int)((blockIdx.x * (unsigned)blockDim.x + threadIdx.x) >> 6);
    int lane = threadIdx.x & 63;
    if (wid >= n_nodes) return;
    float acc = 0.0f;
    int cnt = 0;
#pragma unroll
    for (int g = 0; g < NSHARD; g++) {
        int idx = g * n_nodes + wid;
        int beg = offsets[idx];
        int end = offsets[idx + 1];
        cnt += end - beg;
        int i = beg;
        for (; i + 2 <= end; i += 2) {
            int s0 = csr[i], s1 = csr[i + 1];
            acc += h[s0 * D + lane] + h[s1 * D + lane];
        }
        if (i < end) acc += h[(int)csr[i] * D + lane];
    }
    mean[wid * D + lane] = acc / (float)max(cnt, 1);
}

// out[n][j] = sum_k mean[n][k]*Wl[k][j] + h[n][k]*Wr[k][j] + b[j], optional ReLU.
#define M_TILE 64

__global__ __launch_bounds__(256)
void gemm_kernel(const float* __restrict__ mean, const float* __restrict__ h,
                 const float* __restrict__ Wl, const float* __restrict__ Wr,
                 const float* __restrict__ bias, float* __restrict__ out,
                 int relu, int n_nodes) {
    __shared__ float sWl[D * D];
    __shared__ float sWr[D * D];
    __shared__ float sAm[M_TILE * D];
    __shared__ float sAh[M_TILE * D];

    const int t = threadIdx.x;
    const int n0 = blockIdx.x * M_TILE;

    {
        const float4* wl4 = (const float4*)Wl;
        const float4* wr4 = (const float4*)Wr;
        float4* sWl4 = (float4*)sWl;
        float4* sWr4 = (float4*)sWr;
        for (int i = t; i < 1024; i += 256) {
            sWl4[i] = wl4[i];
            sWr4[i] = wr4[i];
        }
    }
    {
        float4* sAm4 = (float4*)sAm;
        float4* sAh4 = (float4*)sAh;
        const float4* m4 = (const float4*)mean;
        const float4* h4 = (const float4*)h;
        for (int i = t; i < M_TILE * (D / 4); i += 256) {
            int row = i / (D / 4);
            int col = i % (D / 4);
            int node = n0 + row;
            if (node < n_nodes) {
                sAm4[i] = m4[node * (D / 4) + col];
                sAh4[i] = h4[node * (D / 4) + col];
            } else {
                sAm4[i] = make_float4(0.f, 0.f, 0.f, 0.f);
                sAh4[i] = make_float4(0.f, 0.f, 0.f, 0.f);
            }
        }
    }
    __syncthreads();

    const int jp = (t & 31) * 2;
    const int nb = (t >> 5) * 8;

    float acc0[8], acc1[8];
#pragma unroll
    for (int i = 0; i < 8; i++) { acc0[i] = 0.f; acc1[i] = 0.f; }

    for (int k = 0; k < D; k += 4) {
        float2 wl[4], wr[4];
#pragma unroll
        for (int kk = 0; kk < 4; kk++) {
            wl[kk] = *(const float2*)&sWl[(k + kk) * D + jp];
            wr[kk] = *(const float2*)&sWr[(k + kk) * D + jp];
        }
#pragma unroll
        for (int i = 0; i < 8; i++) {
            float4 m4 = *(const float4*)&sAm[(nb + i) * D + k];
            float4 h4 = *(const float4*)&sAh[(nb + i) * D + k];
            acc0[i] += m4.x * wl[0].x + h4.x * wr[0].x;
            acc0[i] += m4.y * wl[1].x + h4.y * wr[1].x;
            acc0[i] += m4.z * wl[2].x + h4.z * wr[2].x;
            acc0[i] += m4.w * wl[3].x + h4.w * wr[3].x;
            acc1[i] += m4.x * wl[0].y + h4.x * wr[0].y;
            acc1[i] += m4.y * wl[1].y + h4.y * wr[1].y;
            acc1[i] += m4.z * wl[2].y + h4.z * wr[2].y;
            acc1[i] += m4.w * wl[3].y + h4.w * wr[3].y;
        }
    }

    float b0 = bias[jp];
    float b1 = bias[jp + 1];
#pragma unroll
    for (int i = 0; i < 8; i++) {
        int node = n0 + nb + i;
        if (node < n_nodes) {
            float v0 = acc0[i] + b0;
            float v1 = acc1[i] + b1;
            if (relu) { v0 = fmaxf(v0, 0.f); v1 = fmaxf(v1, 0.f); }
            *(float2*)&out[node * D + jp] = make_float2(v0, v1);
        }
    }
}

extern "C" void kernel_launch(void* const* d_in, const int* in_sizes, int n_in,
                              void* d_out, int out_size, void* d_ws, size_t ws_size,
                              hipStream_t stream) {
    const float* x  = (const float*)d_in[0];
    const int*   ei = (const int*)d_in[1];
    const int n_nodes = in_sizes[0] / D;     // 50000
    const int n_edges = in_sizes[1] / 2;     // 800000
    const int* src = ei;
    const int* dst = ei + n_edges;

    const float* Wl1 = (const float*)d_in[2];
    const float* Wr1 = (const float*)d_in[3];
    const float* b1  = (const float*)d_in[4];
    const float* Wl2 = (const float*)d_in[5];
    const float* Wr2 = (const float*)d_in[6];
    const float* b2  = (const float*)d_in[7];
    const float* Wl3 = (const float*)d_in[8];
    const float* Wr3 = (const float*)d_in[9];
    const float* b3  = (const float*)d_in[10];

    // Workspace carve-up (256B aligned)
    char* w = (char*)d_ws;
    auto alloc = [&](size_t bytes) -> char* {
        char* p = w;
        w += (bytes + 255) & ~(size_t)255;
        return p;
    };
    const int n_tot = NSHARD * n_nodes;              // 400000
    int*   deg8    = (int*)alloc((size_t)n_tot * 4);
    int*   offsets = (int*)alloc(((size_t)n_tot + 1) * 4);
    int*   cursor  = (int*)alloc((size_t)n_tot * 4);
    int*   partial = (int*)alloc(512 * 4);
    unsigned short* csr = (unsigned short*)alloc((size_t)n_edges * 2);
    float* mean    = (float*)alloc((size_t)n_nodes * D * 4);
    float* h1      = (float*)alloc((size_t)n_nodes * D * 4);
    float* h2      = (float*)d_out;  // layer-3 gemm reads only its own tile rows before writing

    const int eb  = (n_edges + 255) / 256;
    const int zb  = (n_tot + 255) / 256;
    const int nchunks = (n_tot + 1023) / 1024;       // 391 <= 512
    const int agg_blocks  = (n_nodes + 3) / 4;
    const int gemm_blocks = (n_nodes + M_TILE - 1) / M_TILE;

    // CSR build (sharded atomics)
    zero_kernel<<<zb, 256, 0, stream>>>(deg8, n_tot);
    hist_kernel<<<eb, 256, 0, stream>>>(dst, deg8, n_edges, n_nodes);
    partial_kernel<<<nchunks, 256, 0, stream>>>(deg8, partial, n_tot);
    scan_partial_kernel<<<1, 512, 0, stream>>>(partial, offsets, nchunks, n_tot);
    fill_kernel<<<nchunks, 256, 0, stream>>>(deg8, partial, offsets, cursor, n_tot);
    scatter_kernel<<<eb, 256, 0, stream>>>(src, dst, cursor, csr, n_edges, n_nodes);

    // Layer 1: x -> h1 (ReLU)
    agg_kernel<<<agg_blocks, 256, 0, stream>>>(x, offsets, csr, mean, n_nodes);
    gemm_kernel<<<gemm_blocks, 256, 0, stream>>>(mean, x, Wl1, Wr1, b1, h1, 1, n_nodes);

    // Layer 2: h1 -> h2 (ReLU)
    agg_kernel<<<agg_blocks, 256, 0, stream>>>(h1, offsets, csr, mean, n_nodes);
    gemm_kernel<<<gemm_blocks, 256, 0, stream>>>(mean, h1, Wl2, Wr2, b2, h2, 1, n_nodes);

    // Layer 3: h2 -> out (no activation)
    agg_kernel<<<agg_blocks, 256, 0, stream>>>(h2, offsets, csr, mean, n_nodes);
    gemm_kernel<<<gemm_blocks, 256, 0, stream>>>(mean, h2, Wl3, Wr3, b3, (float*)d_out, 0, n_nodes);
}

// Round 5
// 343.766 us; speedup vs baseline: 1.4851x; 1.2807x over previous
//
#include <hip/hip_runtime.h>
#include <hip/hip_bf16.h>

// GraphSAGE 3-layer, N=50000, d=64, E=800000, fp32.
// R5: R4's sharded atomic CSR build (XCD-local, quiet in profile) + NEW:
//  - merged per-node contiguous CSR (second 50k scan + merge copy pass)
//  - agg V2: wave-per-node, 4 neighbor rows per global_load_dwordx4
//    (lane = (neighbor q, float4 group f)), shfl_xor reduce across q.
// R4 post-mortem: agg was 71us x3, latency/MLP-bound (1 row per VMEM inst,
// serial idx->row chains, 8-segment walk). FETCH 88MB = per-XCD compulsory.

#define D 64
#define NSHARD 8

// ---------------- CSR build ----------------

__global__ __launch_bounds__(256)
void zero_kernel(int* __restrict__ p, int n) {
    int i = blockIdx.x * blockDim.x + threadIdx.x;
    if (i < n) p[i] = 0;
}

__global__ __launch_bounds__(256)
void hist_kernel(const int* __restrict__ dst, int* __restrict__ deg8,
                 int n_edges, int n_nodes) {
    int e = blockIdx.x * blockDim.x + threadIdx.x;
    int g = blockIdx.x & (NSHARD - 1);
    if (e < n_edges) {
        int d = dst[e];
        if ((unsigned)d < (unsigned)n_nodes)
            atomicAdd(&deg8[g * n_nodes + d], 1);
    }
}

// per-node total degree (sum over shards)
__global__ __launch_bounds__(256)
void degn_kernel(const int* __restrict__ deg8, int* __restrict__ degN,
                 int n_nodes) {
    int n = blockIdx.x * blockDim.x + threadIdx.x;
    if (n >= n_nodes) return;
    int s = 0;
#pragma unroll
    for (int g = 0; g < NSHARD; g++) s += deg8[g * n_nodes + n];
    degN[n] = s;
}

// Level 1: per-1024-chunk sums.
__global__ __launch_bounds__(256)
void partial_kernel(const int* __restrict__ deg, int* __restrict__ partial,
                    int n_tot) {
    __shared__ int s[256];
    int t = threadIdx.x;
    int base = blockIdx.x * 1024;
    int sum = 0;
#pragma unroll
    for (int k = 0; k < 4; k++) {
        int i = base + k * 256 + t;
        if (i < n_tot) sum += deg[i];
    }
    s[t] = sum;
    __syncthreads();
#pragma unroll
    for (int off = 128; off > 0; off >>= 1) {
        if (t < off) s[t] += s[t + off];
        __syncthreads();
    }
    if (t == 0) partial[blockIdx.x] = s[0];
}

// Level 2: exclusive scan of (<=512) chunk partials; writes total at offsets[n_tot].
__global__ __launch_bounds__(512)
void scan_partial_kernel(int* __restrict__ partial, int* __restrict__ offsets,
                         int nchunks, int n_tot) {
    __shared__ int s[512];
    int t = threadIdx.x;
    s[t] = (t < nchunks) ? partial[t] : 0;
    __syncthreads();
#pragma unroll
    for (int off = 1; off < 512; off <<= 1) {
        int u = 0;
        if (t >= off) u = s[t - off];
        __syncthreads();
        if (t >= off) s[t] += u;
        __syncthreads();
    }
    if (t < nchunks) partial[t] = (t > 0) ? s[t - 1] : 0;
    if (t == 0) offsets[n_tot] = s[511];
}

// Level 3: block-local scan of 1024 entries (4/thread) + chunk base.
__global__ __launch_bounds__(256)
void fill_kernel(const int* __restrict__ deg, const int* __restrict__ partial,
                 int* __restrict__ offsets, int* __restrict__ cursor, int n_tot) {
    __shared__ int s[256];
    int t = threadIdx.x;
    int base = blockIdx.x * 1024;
    int i0 = base + 4 * t;
    int v0 = 0, v1 = 0, v2 = 0, v3 = 0;
    if (i0 + 3 < n_tot) {
        int4 v = *(const int4*)&deg[i0];
        v0 = v.x; v1 = v.y; v2 = v.z; v3 = v.w;
    } else {
        if (i0 + 0 < n_tot) v0 = deg[i0 + 0];
        if (i0 + 1 < n_tot) v1 = deg[i0 + 1];
        if (i0 + 2 < n_tot) v2 = deg[i0 + 2];
        if (i0 + 3 < n_tot) v3 = deg[i0 + 3];
    }
    int mysum = v0 + v1 + v2 + v3;
    s[t] = mysum;
    __syncthreads();
#pragma unroll
    for (int off = 1; off < 256; off <<= 1) {
        int u = 0;
        if (t >= off) u = s[t - off];
        __syncthreads();
        if (t >= off) s[t] += u;
        __syncthreads();
    }
    int excl = partial[blockIdx.x] + ((t > 0) ? s[t - 1] : 0);
    int o0 = excl, o1 = o0 + v0, o2 = o1 + v1, o3 = o2 + v2;
    if (i0 + 3 < n_tot) {
        *(int4*)&offsets[i0] = make_int4(o0, o1, o2, o3);
        *(int4*)&cursor[i0]  = make_int4(o0, o1, o2, o3);
    } else {
        if (i0 + 0 < n_tot) { offsets[i0 + 0] = o0; cursor[i0 + 0] = o0; }
        if (i0 + 1 < n_tot) { offsets[i0 + 1] = o1; cursor[i0 + 1] = o1; }
        if (i0 + 2 < n_tot) { offsets[i0 + 2] = o2; cursor[i0 + 2] = o2; }
        if (i0 + 3 < n_tot) { offsets[i0 + 3] = o3; cursor[i0 + 3] = o3; }
    }
}

__global__ __launch_bounds__(256)
void scatter_kernel(const int* __restrict__ src, const int* __restrict__ dst,
                    int* __restrict__ cursor, unsigned short* __restrict__ csr,
                    int n_edges, int n_nodes) {
    int e = blockIdx.x * blockDim.x + threadIdx.x;
    int g = blockIdx.x & (NSHARD - 1);
    if (e < n_edges) {
        int d = dst[e];
        if ((unsigned)d < (unsigned)n_nodes) {
            int s = src[e];
            if ((unsigned)s >= (unsigned)n_nodes) s = 0;
            int p = atomicAdd(&cursor[g * n_nodes + d], 1);
            csr[p] = (unsigned short)s;
        }
    }
}

// Gather node n's 8 shard-segments into one contiguous run at offsetsM[n].
__global__ __launch_bounds__(256)
void merge_kernel(const unsigned short* __restrict__ csr,
                  const int* __restrict__ offsets8,
                  const int* __restrict__ offsetsM,
                  unsigned short* __restrict__ csrM, int n_nodes) {
    int n = blockIdx.x * blockDim.x + threadIdx.x;
    if (n >= n_nodes) return;
    int pos = offsetsM[n];
#pragma unroll
    for (int g = 0; g < NSHARD; g++) {
        int beg = offsets8[g * n_nodes + n];
        int end = offsets8[g * n_nodes + n + 1];
        for (int i = beg; i < end; i++) csrM[pos++] = csr[i];
    }
}

// ---------------- Per-layer kernels ----------------

// Wave per node. lane -> (q = neighbor slot 0..3, f = float4 group 0..15).
// Each global_load_dwordx4 fetches 4 neighbor rows (1KB). shfl_xor reduce.
__global__ __launch_bounds__(256)
void agg_kernel(const float* __restrict__ h, const int* __restrict__ offM,
                const unsigned short* __restrict__ csrM, float* __restrict__ mean,
                int n_nodes) {
    int wid = (int)((blockIdx.x * (unsigned)blockDim.x + threadIdx.x) >> 6);
    int lane = threadIdx.x & 63;
    if (wid >= n_nodes) return;
    int beg = offM[wid];
    int end = offM[wid + 1];
    int q = lane >> 4;
    int f = lane & 15;
    const float4* h4 = (const float4*)h;

    float ax = 0.f, ay = 0.f, az = 0.f, aw = 0.f;
    float bx = 0.f, by = 0.f, bz = 0.f, bw = 0.f;
    int i = beg + q;
    for (; i + 4 < end; i += 8) {
        int s0 = csrM[i];
        int s1 = csrM[i + 4];
        float4 v0 = h4[s0 * 16 + f];
        float4 v1 = h4[s1 * 16 + f];
        ax += v0.x; ay += v0.y; az += v0.z; aw += v0.w;
        bx += v1.x; by += v1.y; bz += v1.z; bw += v1.w;
    }
    if (i < end) {
        int s0 = csrM[i];
        float4 v0 = h4[s0 * 16 + f];
        ax += v0.x; ay += v0.y; az += v0.z; aw += v0.w;
    }
    ax += bx; ay += by; az += bz; aw += bw;

#pragma unroll
    for (int m = 16; m < 64; m <<= 1) {
        ax += __shfl_xor(ax, m, 64);
        ay += __shfl_xor(ay, m, 64);
        az += __shfl_xor(az, m, 64);
        aw += __shfl_xor(aw, m, 64);
    }

    if (lane < 16) {
        float inv = 1.0f / (float)max(end - beg, 1);
        float4 r;
        r.x = ax * inv; r.y = ay * inv; r.z = az * inv; r.w = aw * inv;
        ((float4*)mean)[wid * 16 + f] = r;
    }
}

// out[n][j] = sum_k mean[n][k]*Wl[k][j] + h[n][k]*Wr[k][j] + b[j], optional ReLU.
#define M_TILE 64

__global__ __launch_bounds__(256)
void gemm_kernel(const float* __restrict__ mean, const float* __restrict__ h,
                 const float* __restrict__ Wl, const float* __restrict__ Wr,
                 const float* __restrict__ bias, float* __restrict__ out,
                 int relu, int n_nodes) {
    __shared__ float sWl[D * D];
    __shared__ float sWr[D * D];
    __shared__ float sAm[M_TILE * D];
    __shared__ float sAh[M_TILE * D];

    const int t = threadIdx.x;
    const int n0 = blockIdx.x * M_TILE;

    {
        const float4* wl4 = (const float4*)Wl;
        const float4* wr4 = (const float4*)Wr;
        float4* sWl4 = (float4*)sWl;
        float4* sWr4 = (float4*)sWr;
        for (int i = t; i < 1024; i += 256) {
            sWl4[i] = wl4[i];
            sWr4[i] = wr4[i];
        }
    }
    {
        float4* sAm4 = (float4*)sAm;
        float4* sAh4 = (float4*)sAh;
        const float4* m4 = (const float4*)mean;
        const float4* h4 = (const float4*)h;
        for (int i = t; i < M_TILE * (D / 4); i += 256) {
            int row = i / (D / 4);
            int col = i % (D / 4);
            int node = n0 + row;
            if (node < n_nodes) {
                sAm4[i] = m4[node * (D / 4) + col];
                sAh4[i] = h4[node * (D / 4) + col];
            } else {
                sAm4[i] = make_float4(0.f, 0.f, 0.f, 0.f);
                sAh4[i] = make_float4(0.f, 0.f, 0.f, 0.f);
            }
        }
    }
    __syncthreads();

    const int jp = (t & 31) * 2;
    const int nb = (t >> 5) * 8;

    float acc0[8], acc1[8];
#pragma unroll
    for (int i = 0; i < 8; i++) { acc0[i] = 0.f; acc1[i] = 0.f; }

    for (int k = 0; k < D; k += 4) {
        float2 wl[4], wr[4];
#pragma unroll
        for (int kk = 0; kk < 4; kk++) {
            wl[kk] = *(const float2*)&sWl[(k + kk) * D + jp];
            wr[kk] = *(const float2*)&sWr[(k + kk) * D + jp];
        }
#pragma unroll
        for (int i = 0; i < 8; i++) {
            float4 m4 = *(const float4*)&sAm[(nb + i) * D + k];
            float4 h4 = *(const float4*)&sAh[(nb + i) * D + k];
            acc0[i] += m4.x * wl[0].x + h4.x * wr[0].x;
            acc0[i] += m4.y * wl[1].x + h4.y * wr[1].x;
            acc0[i] += m4.z * wl[2].x + h4.z * wr[2].x;
            acc0[i] += m4.w * wl[3].x + h4.w * wr[3].x;
            acc1[i] += m4.x * wl[0].y + h4.x * wr[0].y;
            acc1[i] += m4.y * wl[1].y + h4.y * wr[1].y;
            acc1[i] += m4.z * wl[2].y + h4.z * wr[2].y;
            acc1[i] += m4.w * wl[3].y + h4.w * wr[3].y;
        }
    }

    float b0 = bias[jp];
    float b1 = bias[jp + 1];
#pragma unroll
    for (int i = 0; i < 8; i++) {
        int node = n0 + nb + i;
        if (node < n_nodes) {
            float v0 = acc0[i] + b0;
            float v1 = acc1[i] + b1;
            if (relu) { v0 = fmaxf(v0, 0.f); v1 = fmaxf(v1, 0.f); }
            *(float2*)&out[node * D + jp] = make_float2(v0, v1);
        }
    }
}

extern "C" void kernel_launch(void* const* d_in, const int* in_sizes, int n_in,
                              void* d_out, int out_size, void* d_ws, size_t ws_size,
                              hipStream_t stream) {
    const float* x  = (const float*)d_in[0];
    const int*   ei = (const int*)d_in[1];
    const int n_nodes = in_sizes[0] / D;     // 50000
    const int n_edges = in_sizes[1] / 2;     // 800000
    const int* src = ei;
    const int* dst = ei + n_edges;

    const float* Wl1 = (const float*)d_in[2];
    const float* Wr1 = (const float*)d_in[3];
    const float* b1  = (const float*)d_in[4];
    const float* Wl2 = (const float*)d_in[5];
    const float* Wr2 = (const float*)d_in[6];
    const float* b2  = (const float*)d_in[7];
    const float* Wl3 = (const float*)d_in[8];
    const float* Wr3 = (const float*)d_in[9];
    const float* b3  = (const float*)d_in[10];

    // Workspace carve-up (256B aligned)
    char* w = (char*)d_ws;
    auto alloc = [&](size_t bytes) -> char* {
        char* p = w;
        w += (bytes + 255) & ~(size_t)255;
        return p;
    };
    const int n_tot = NSHARD * n_nodes;              // 400000
    int*   deg8     = (int*)alloc((size_t)n_tot * 4);
    int*   offsets8 = (int*)alloc(((size_t)n_tot + 1) * 4);
    int*   cursor8  = (int*)alloc((size_t)n_tot * 4);
    int*   degN     = (int*)alloc((size_t)n_nodes * 4);
    int*   offsetsM = (int*)alloc(((size_t)n_nodes + 1) * 4);
    int*   cursorN  = (int*)alloc((size_t)n_nodes * 4);   // scratch (fill writes it)
    int*   partial  = (int*)alloc(512 * 4);
    unsigned short* csr  = (unsigned short*)alloc((size_t)n_edges * 2);
    unsigned short* csrM = (unsigned short*)alloc((size_t)n_edges * 2);
    float* mean     = (float*)alloc((size_t)n_nodes * D * 4);
    float* h1       = (float*)alloc((size_t)n_nodes * D * 4);
    float* h2       = (float*)d_out;  // layer-3 gemm reads only its own tile rows before writing

    const int eb  = (n_edges + 255) / 256;
    const int nb  = (n_nodes + 255) / 256;
    const int zb  = (n_tot + 255) / 256;
    const int nchunks8 = (n_tot + 1023) / 1024;      // 391 <= 512
    const int nchunksN = (n_nodes + 1023) / 1024;    // 49  <= 512
    const int agg_blocks  = (n_nodes + 3) / 4;
    const int gemm_blocks = (n_nodes + M_TILE - 1) / M_TILE;

    // CSR build (sharded atomics, then merge to per-node contiguous)
    zero_kernel<<<zb, 256, 0, stream>>>(deg8, n_tot);
    hist_kernel<<<eb, 256, 0, stream>>>(dst, deg8, n_edges, n_nodes);
    // scan #1: [shard][node] -> offsets8/cursor8 (scatter targets)
    partial_kernel<<<nchunks8, 256, 0, stream>>>(deg8, partial, n_tot);
    scan_partial_kernel<<<1, 512, 0, stream>>>(partial, offsets8, nchunks8, n_tot);
    fill_kernel<<<nchunks8, 256, 0, stream>>>(deg8, partial, offsets8, cursor8, n_tot);
    // scan #2: per-node totals -> offsetsM (merged layout)
    degn_kernel<<<nb, 256, 0, stream>>>(deg8, degN, n_nodes);
    partial_kernel<<<nchunksN, 256, 0, stream>>>(degN, partial, n_nodes);
    scan_partial_kernel<<<1, 512, 0, stream>>>(partial, offsetsM, nchunksN, n_nodes);
    fill_kernel<<<nchunksN, 256, 0, stream>>>(degN, partial, offsetsM, cursorN, n_nodes);
    // scatter into sharded csr, then merge per node
    scatter_kernel<<<eb, 256, 0, stream>>>(src, dst, cursor8, csr, n_edges, n_nodes);
    merge_kernel<<<nb, 256, 0, stream>>>(csr, offsets8, offsetsM, csrM, n_nodes);

    // Layer 1: x -> h1 (ReLU)
    agg_kernel<<<agg_blocks, 256, 0, stream>>>(x, offsetsM, csrM, mean, n_nodes);
    gemm_kernel<<<gemm_blocks, 256, 0, stream>>>(mean, x, Wl1, Wr1, b1, h1, 1, n_nodes);

    // Layer 2: h1 -> h2 (ReLU)
    agg_kernel<<<agg_blocks, 256, 0, stream>>>(h1, offsetsM, csrM, mean, n_nodes);
    gemm_kernel<<<gemm_blocks, 256, 0, stream>>>(mean, h1, Wl2, Wr2, b2, h2, 1, n_nodes);

    // Layer 3: h2 -> out (no activation)
    agg_kernel<<<agg_blocks, 256, 0, stream>>>(h2, offsetsM, csrM, mean, n_nodes);
    gemm_kernel<<<gemm_blocks, 256, 0, stream>>>(mean, h2, Wl3, Wr3, b3, (float*)d_out, 0, n_nodes);
}